// Round 1
// baseline (182.470 us; speedup 1.0000x reference)
//
#include <hip/hip_runtime.h>

typedef unsigned short u16;
typedef unsigned int   u32;
typedef unsigned long long u64;
typedef __attribute__((ext_vector_type(8))) short bf16x8;
typedef __attribute__((ext_vector_type(4))) float f32x4;

#define NOBS 128
#define NN   1280
#define NH   256
#define NO   80
#define TT   5
#define RR   16          // batch rows per block
#define NTHR 512         // 8 waves/block, 2 col-tiles per wave
#define BP1  88          // layer1 bits LDS pitch (u16)
#define BP2  20          // layer2/3 bits pitch (u16)

// ws layout (u16 units), stage-contiguous: [kc][ks][sel][rows][32], rows
// XOR-swizzled within (see prep). W1s [20][2][3][256][32] @0 ;
// W2s [4][2][3][256][32] @983040 ; Wos [4][2][3][128][32] @1179648 (pad128)
#define W1TOT   983040
#define W2S_OFF 983040
#define WOS_OFF 1179648
#define WS_TOTAL 1277952

#define PREP_BLOCKS 4992          // WS_TOTAL/256

#define VMW2()  asm volatile("s_waitcnt vmcnt(2)" ::: "memory")
#define VMW0()  asm volatile("s_waitcnt vmcnt(0)" ::: "memory")
#define FENCE() asm volatile("" ::: "memory")

__device__ __forceinline__ float bf2f(u16 u) {
  union { u32 i; float f; } x; x.i = ((u32)u) << 16; return x.f;
}
__device__ __forceinline__ u16 f2bf(float f) {
  union { float f; u32 i; } x; x.f = f;
  u32 i = x.i + 0x7FFFu + ((x.i >> 16) & 1u);   // RNE
  return (u16)(i >> 16);
}

// 3-way bf16 split: w ~= hi + mid + lo, residual <= 2^-27 |w|.
__device__ __forceinline__ u16 split3(float w, int sel) {
  u16 hi = f2bf(w);
  if (sel == 0) return hi;
  float r1 = __fsub_rn(w, bf2f(hi));        // exact
  u16 mid = f2bf(r1);
  if (sel == 1) return mid;
  float r2 = __fsub_rn(r1, bf2f(mid));      // exact
  return f2bf(r2);
}

// Inline near-correctly-rounded f32 exp via f64 degree-11 Taylor.
__device__ __forceinline__ float exp_cr(float arg) {
  double xa = (double)arg;
  double nd = __builtin_rint(xa * 1.4426950408889634074);
  double r  = fma(nd, -6.93147180369123816490e-01, xa);
  r         = fma(nd, -1.90821492927058770002e-10, r);
  double p = 2.50521083854417187751e-08;
  p = fma(p, r, 2.75573192239858906526e-07);
  p = fma(p, r, 2.75573192239858906526e-06);
  p = fma(p, r, 2.48015873015873015873e-05);
  p = fma(p, r, 1.98412698412698412698e-04);
  p = fma(p, r, 1.38888888888888888889e-03);
  p = fma(p, r, 8.33333333333333333333e-03);
  p = fma(p, r, 4.16666666666666666667e-02);
  p = fma(p, r, 1.66666666666666666667e-01);
  p = fma(p, r, 0.5);
  p = fma(p, r, 1.0);
  p = fma(p, r, 1.0);
  int n = (int)nd;
  union { u64 u; double d; } s;
  s.u = ((u64)(u32)(n + 1023)) << 52;
  return (n < -150) ? 0.f : (float)(s.d * p);
}

// Weight-split-only prep: stage-contiguous, bank-swizzled layout.
// Swizzle: sub-fragment s (8 u16) of row j stored at position s ^ ((j>>1)&3)
// -> wave b128 reads are 2-way max. The encoder is now fused into snn_main
// (its output is block-local: each block only reads its own 16 rows' bits).
__global__ __launch_bounds__(256) void prep_w(
    const float* __restrict__ W1, const float* __restrict__ W2,
    const float* __restrict__ Wo, u16* __restrict__ ws)
{
  int i = blockIdx.x * 256 + threadIdx.x;   // < WS_TOTAL exactly
  if (i < W1TOT) {                          // W1 [256][1280]
    int kc = i / 49152, r = i - kc * 49152;
    int ks = r / 24576, r2 = r - ks * 24576;
    int sel = r2 / 8192, r3 = r2 & 8191;
    int j = r3 >> 5, kkpos = r3 & 31;
    int kk = ((kkpos >> 3) ^ ((j >> 1) & 3)) * 8 + (kkpos & 7);
    ws[i] = split3(W1[j * 1280 + kc * 64 + ks * 32 + kk], sel);
  } else if (i < WOS_OFF) {                 // W2 [256][256]
    int i2 = i - W2S_OFF;
    int kc = i2 / 49152, r = i2 - kc * 49152;
    int ks = r / 24576, r2 = r - ks * 24576;
    int sel = r2 / 8192, r3 = r2 & 8191;
    int j = r3 >> 5, kkpos = r3 & 31;
    int kk = ((kkpos >> 3) ^ ((j >> 1) & 3)) * 8 + (kkpos & 7);
    ws[i] = split3(W2[j * 256 + kc * 64 + ks * 32 + kk], sel);
  } else {                                  // Wo [80][256] padded to 128 rows
    int i3 = i - WOS_OFF;
    int kc = i3 / 24576, r = i3 - kc * 24576;
    int ks = r / 12288, r2 = r - ks * 12288;
    int sel = r2 / 4096, r3 = r2 & 4095;
    int j = r3 >> 5, kkpos = r3 & 31;
    int kk = ((kkpos >> 3) ^ ((j >> 1) & 3)) * 8 + (kkpos & 7);
    float w = (j < NO) ? Wo[j * 256 + kc * 64 + ks * 32 + kk] : 0.f;
    ws[i] = split3(w, sel);
  }
}

// DMA this wave's 2KB stage slice (1024 u16) into LDS: 2 instructions,
// wave-uniform LDS base + implicit lane*16.
__device__ __forceinline__ void dma2(const u16* __restrict__ src, u16* dst, int lane) {
  __builtin_amdgcn_global_load_lds((const u32*)(src + lane * 8), (u32*)dst, 16, 0, 0);
  __builtin_amdgcn_global_load_lds((const u32*)(src + 512 + lane * 8),
                                   (u32*)(dst + 512), 16, 0, 0);
}

// Barrier-free wave-private staged GEMM: each wave DMAs only the 32 B-rows it
// reads (2KB/stage) into its own triple-buffered LDS slice; pacing is per-wave
// s_waitcnt vmcnt(2) (one full stage of slack). FINAL stage waits vmcnt(0) —
// its own DMAs are the only ones left in flight (R16's race: vmcnt(2) was
// already satisfied and read unlanded data). 6 stages per kcks, 3 bufs ->
// buffer index == sel. Per-column accumulation order
// kc:(ks0:hi,mid,lo),(ks1:hi,mid,lo) — bit-identical to R13/R14/R15.
__device__ __forceinline__ void gemm_wp(
    const u16* lbits, int bpitch,
    const u16* __restrict__ wsbase, int nkc, int selblk,
    u16* mybuf,                     // this wave's [3][1024] u16 slices
    int wv, int lane, f32x4 acc[2][TT])
{
  const int m16 = lane & 15, q = lane >> 4;
  const int swz = (q ^ ((m16 >> 1) & 3)) * 8;
  const int lro0 = m16 * 32 + swz;           // local row m16
  const int lro1 = lro0 + 512;               // local row m16+16
  const int sh = q * 8;
  const int nst = nkc * 6;
  const u16* slice = wsbase + wv * 1024;

  dma2(slice, mybuf, lane);                  // st 0 -> buf 0
  dma2(slice + selblk, mybuf + 1024, lane);  // st 1 -> buf 1
  FENCE();

  int st = 0;
  for (int kcks = 0; kcks < nkc * 2; ++kcks) {
    const int kc = kcks >> 1, ks = kcks & 1;
    bf16x8 afr[TT];
    #pragma unroll
    for (int t = 0; t < TT; ++t) {
      u32 bwv = *(const u32*)(lbits + (t * RR + m16) * bpitch + kc * 4 + ks * 2);
      u32 b = (bwv >> sh) & 0xFFu;
      union { u32 u[4]; bf16x8 v; } x;
      #pragma unroll
      for (int i = 0; i < 4; ++i)
        x.u[i] = ((((b >> (2 * i)) & 3u) * 0x8001u) & 0x00010001u) * 0x3F80u;
      afr[t] = x.v;
    }
    #pragma unroll
    for (int sel = 0; sel < 3; ++sel, ++st) {
      u16* cur = mybuf + sel * 1024;         // st % 3 == sel (6 stages/kcks)
      if (st + 1 < nst) { VMW2(); } else { VMW0(); }   // last stage: own DMAs are the tail
      const bf16x8 bf0 = *(const bf16x8*)(cur + lro0);
      const bf16x8 bf1 = *(const bf16x8*)(cur + lro1);
      #pragma unroll
      for (int t = 0; t < TT; ++t)
        acc[0][t] = __builtin_amdgcn_mfma_f32_16x16x32_bf16(afr[t], bf0, acc[0][t], 0, 0, 0);
      #pragma unroll
      for (int t = 0; t < TT; ++t)
        acc[1][t] = __builtin_amdgcn_mfma_f32_16x16x32_bf16(afr[t], bf1, acc[1][t], 0, 0, 0);
      FENCE();
      if (st + 2 < nst)                      // st+2 -> buf (sel+2)%3 (consumed)
        dma2(slice + (st + 2) * selblk, mybuf + ((sel + 2) % 3) * 1024, lane);
      FENCE();
    }
  }
}

// LIF recurrence over t; emit spike bits via ballot. 2 col-tiles per wave.
__device__ __forceinline__ void recur_spikes2(
    f32x4 acc[2][TT], const float* __restrict__ bias,
    int lane, int wv, u16* sbits, int spitch)
{
  const int q = lane >> 4, m16 = lane & 15;
  #pragma unroll
  for (int i = 0; i < 2; ++i) {
    int ct = wv * 2 + i;
    int j = ct * 16 + m16;
    float bj = bias[j];
    #pragma unroll
    for (int rg = 0; rg < 4; ++rg) {
      float c = 0.f, v = 0.f, sprev = 0.f;
      #pragma unroll
      for (int t = 0; t < TT; ++t) {
        float u = acc[i][t][rg];
        c = __fadd_rn(__fadd_rn(__fmul_rn(c, 0.5f), u), bj);       // (c*0.5 + u) + b
        float vd = __fmul_rn(v, 0.75f);
        v = __fadd_rn((sprev > 0.5f) ? 0.f : vd, c);               // v*0.75*(1-s) + c
        bool sp = v > 0.5f;
        u64 mask = __ballot(sp);
        if (m16 == 0) {
          int row = q * 4 + rg;
          sbits[(t * RR + row) * spitch + ct] = (u16)(mask >> (q * 16));
        }
        sprev = sp ? 1.f : 0.f;
      }
    }
  }
}

__global__ __launch_bounds__(NTHR, 4) void snn_main(
    const float* __restrict__ obs, const float* __restrict__ enc_mean,
    const float* __restrict__ enc_std,
    const float* __restrict__ b1, const float* __restrict__ b2, const float* __restrict__ bo,
    const float* __restrict__ dec_w, const float* __restrict__ dec_b, const float* __restrict__ log_std,
    const u16* __restrict__ wsW, float* __restrict__ out, int Btot)
{
  __shared__ __align__(16) u16 smem[37376];          // 74,752 B -> 2 blocks/CU
  u16* bufs = smem;                                  // [8 waves][3][1024]
  u16* encb = smem + 24576;                          // [5t*16r][BP1] = 7040
  u16* s1b  = encb + 7040;                           // [5t*16r][BP2] = 1600
  u16* s2b  = s1b + 1600;                            // 1600
  float* soacc = (float*)(s2b + 1600);               // [16][80] f32 (own region)

  const int tid  = threadIdx.x;
  const int lane = tid & 63;
  const int wv   = tid >> 6;          // 0..7
  const int r0   = blockIdx.x * RR;
  u16* mybuf = bufs + wv * 3072;

  // ---------- fused population encoder: 16 rows x 1280 cols -> bit-planes ----
  // Arithmetic bit-identical to the old prep encoder (same exp_cr, same order);
  // output goes straight to LDS, never touching HBM.
  for (int it = tid; it < RR * 80; it += NTHR) {     // 1280 items, <=3 rounds
    int r = it / 80, w = it - (it / 80) * 80;
    const float* obsrow = obs + (r0 + r) * NOBS;
    u32 wbits[TT] = {0, 0, 0, 0, 0};
    #pragma unroll 4
    for (int e = 0; e < 16; ++e) {
      int k = w * 16 + e;
      int f = k / 10;
      float x  = obsrow[f];
      float m  = enc_mean[k];
      float sd = enc_std[k];
      float d  = __fsub_rn(x, m);
      float arg = __fdiv_rn(__fmul_rn(-0.5f, __fmul_rn(d, d)), __fmul_rn(sd, sd));
      float a = exp_cr(arg);
      float v = 0.f;
      #pragma unroll
      for (int t = 0; t < TT; ++t) {
        v = __fadd_rn(v, a);
        if (v > 0.999f) { wbits[t] |= (1u << e); v = __fsub_rn(v, 0.999f); }
      }
    }
    #pragma unroll
    for (int t = 0; t < TT; ++t)
      encb[(t * RR + r) * BP1 + w] = (u16)wbits[t];
  }
  __syncthreads();

  f32x4 acc[2][TT];
  const f32x4 zero4 = {0.f, 0.f, 0.f, 0.f};
#define ZERO_ACC() { _Pragma("unroll") for (int i = 0; i < 2; ++i) \
                     _Pragma("unroll") for (int t = 0; t < TT; ++t) acc[i][t] = zero4; }

  // ---------- layer 1: [80 x 1280] @ [1280 x 256] (3-way split fused) ----------
  ZERO_ACC();
  gemm_wp(encb, BP1, wsW, 20, 8192, mybuf, wv, lane, acc);
  recur_spikes2(acc, b1, lane, wv, s1b, BP2);
  __syncthreads();

  // ---------- layer 2: [80 x 256] @ [256 x 256] ----------
  ZERO_ACC();
  gemm_wp(s1b, BP2, wsW + W2S_OFF, 4, 8192, mybuf, wv, lane, acc);
  recur_spikes2(acc, b2, lane, wv, s2b, BP2);
  __syncthreads();

  // ---------- layer 3: [80 x 256] @ [256 x 80(pad96 of 128)] — waves 0..2 ----------
  if (wv < 3) {
    ZERO_ACC();
    gemm_wp(s2b, BP2, wsW + WOS_OFF, 4, 4096, mybuf, wv, lane, acc);
    const int q = lane >> 4, m16 = lane & 15;
    #pragma unroll
    for (int i = 0; i < 2; ++i) {
      int j = (wv * 2 + i) * 16 + m16;
      bool valid = j < NO;
      float bj = valid ? bo[j] : 0.f;
      #pragma unroll
      for (int rg = 0; rg < 4; ++rg) {
        float c = 0.f, v = 0.f, sprev = 0.f;
        int cnt = 0;
        #pragma unroll
        for (int t = 0; t < TT; ++t) {
          float u = acc[i][t][rg];
          c = __fadd_rn(__fadd_rn(__fmul_rn(c, 0.5f), u), bj);
          float vd = __fmul_rn(v, 0.75f);
          v = __fadd_rn((sprev > 0.5f) ? 0.f : vd, c);
          bool sp = v > 0.5f;
          cnt += sp ? 1 : 0;
          sprev = sp ? 1.f : 0.f;
        }
        if (valid) soacc[(q * 4 + rg) * NO + j] = __fdiv_rn((float)cnt, 5.0f);
      }
    }
  }
  __syncthreads();

  // ---------- decoder: grouped dot + ELU ----------
  if (tid < RR * 8) {
    int r = tid >> 3, a = tid & 7;
    float s = 0.f;
    const float* so = soacc + r * NO + a * 10;
    #pragma unroll
    for (int p = 0; p < 10; ++p)
      s = __fadd_rn(s, __fmul_rn(so[p], dec_w[a * 10 + p]));
    s = __fadd_rn(s, dec_b[a]);
    float mu = (s > 0.f) ? s : expm1f(s);
    out[(r0 + r) * 8 + a] = mu;
  }
  if (blockIdx.x == 0 && tid < 8) {
    out[Btot * 8 + tid] = expf(log_std[tid]);
  }
}

extern "C" void kernel_launch(void* const* d_in, const int* in_sizes, int n_in,
                              void* d_out, int out_size, void* d_ws, size_t ws_size,
                              hipStream_t stream) {
  const float* obs      = (const float*)d_in[0];
  const float* enc_mean = (const float*)d_in[1];
  const float* enc_std  = (const float*)d_in[2];
  const float* W1       = (const float*)d_in[3];
  const float* b1       = (const float*)d_in[4];
  const float* W2       = (const float*)d_in[5];
  const float* b2       = (const float*)d_in[6];
  const float* Wo       = (const float*)d_in[7];
  const float* bo       = (const float*)d_in[8];
  const float* dec_w    = (const float*)d_in[9];
  const float* dec_b    = (const float*)d_in[10];
  const float* log_std  = (const float*)d_in[11];
  u16*   ws  = (u16*)d_ws;
  float* out = (float*)d_out;
  int B = in_sizes[0] / NOBS;   // 8192

  hipLaunchKernelGGL(prep_w, dim3(PREP_BLOCKS), dim3(256), 0, stream,
                     W1, W2, Wo, ws);
  hipLaunchKernelGGL(snn_main, dim3(B / RR), dim3(NTHR), 0, stream,
                     obs, enc_mean, enc_std, b1, b2, bo, dec_w, dec_b, log_std,
                     ws, out, B);
}

// Round 2
// 177.953 us; speedup vs baseline: 1.0254x; 1.0254x over previous
//
#include <hip/hip_runtime.h>

typedef unsigned char  u8;
typedef unsigned short u16;
typedef unsigned int   u32;
typedef unsigned long long u64;
typedef __attribute__((ext_vector_type(8))) short bf16x8;
typedef __attribute__((ext_vector_type(4))) float f32x4;

#define NOBS 128
#define NN   1280
#define NH   256
#define NO   80
#define TT   5
#define RR   16          // batch rows per block
#define NTHR 512         // 8 waves/block, 2 col-tiles per wave
#define BP1  88          // layer1 bits LDS pitch (u16)
#define BP2  20          // layer2/3 bits pitch (u16)

// ws layout (u16 units), stage-contiguous: [kc][ks][sel][rows][32], rows
// XOR-swizzled within (see prep). W1s [20][2][3][256][32] @0 ;
// W2s [4][2][3][256][32] @983040 ; Wos [4][2][3][128][32] @1179648 (pad128)
#define W1TOT   983040
#define W2S_OFF 983040
#define WOS_OFF 1179648
#define WS_TOTAL 1277952

#define PREP_BLOCKS 4992          // WS_TOTAL/256

#define VMW2()  asm volatile("s_waitcnt vmcnt(2)" ::: "memory")
#define VMW0()  asm volatile("s_waitcnt vmcnt(0)" ::: "memory")
#define FENCE() asm volatile("" ::: "memory")

__device__ __forceinline__ float bf2f(u16 u) {
  union { u32 i; float f; } x; x.i = ((u32)u) << 16; return x.f;
}
__device__ __forceinline__ u16 f2bf(float f) {
  union { float f; u32 i; } x; x.f = f;
  u32 i = x.i + 0x7FFFu + ((x.i >> 16) & 1u);   // RNE
  return (u16)(i >> 16);
}

// 3-way bf16 split: w ~= hi + mid + lo, residual <= 2^-27 |w|.
__device__ __forceinline__ u16 split3(float w, int sel) {
  u16 hi = f2bf(w);
  if (sel == 0) return hi;
  float r1 = __fsub_rn(w, bf2f(hi));        // exact
  u16 mid = f2bf(r1);
  if (sel == 1) return mid;
  float r2 = __fsub_rn(r1, bf2f(mid));      // exact
  return f2bf(r2);
}

// Inline near-correctly-rounded f32 exp via f64 degree-11 Taylor.
__device__ __forceinline__ float exp_cr(float arg) {
  double xa = (double)arg;
  double nd = __builtin_rint(xa * 1.4426950408889634074);
  double r  = fma(nd, -6.93147180369123816490e-01, xa);
  r         = fma(nd, -1.90821492927058770002e-10, r);
  double p = 2.50521083854417187751e-08;
  p = fma(p, r, 2.75573192239858906526e-07);
  p = fma(p, r, 2.75573192239858906526e-06);
  p = fma(p, r, 2.48015873015873015873e-05);
  p = fma(p, r, 1.98412698412698412698e-04);
  p = fma(p, r, 1.38888888888888888889e-03);
  p = fma(p, r, 8.33333333333333333333e-03);
  p = fma(p, r, 4.16666666666666666667e-02);
  p = fma(p, r, 1.66666666666666666667e-01);
  p = fma(p, r, 0.5);
  p = fma(p, r, 1.0);
  p = fma(p, r, 1.0);
  int n = (int)nd;
  union { u64 u; double d; } s;
  s.u = ((u64)(u32)(n + 1023)) << 52;
  return (n < -150) ? 0.f : (float)(s.d * p);
}

// Weight-split-only prep: stage-contiguous, bank-swizzled layout.
// Swizzle: sub-fragment s (8 u16) of row j stored at position s ^ ((j>>1)&3)
// -> wave b128 reads are 2-way max.
__global__ __launch_bounds__(256) void prep_w(
    const float* __restrict__ W1, const float* __restrict__ W2,
    const float* __restrict__ Wo, u16* __restrict__ ws)
{
  int i = blockIdx.x * 256 + threadIdx.x;   // < WS_TOTAL exactly
  if (i < W1TOT) {                          // W1 [256][1280]
    int kc = i / 49152, r = i - kc * 49152;
    int ks = r / 24576, r2 = r - ks * 24576;
    int sel = r2 / 8192, r3 = r2 & 8191;
    int j = r3 >> 5, kkpos = r3 & 31;
    int kk = ((kkpos >> 3) ^ ((j >> 1) & 3)) * 8 + (kkpos & 7);
    ws[i] = split3(W1[j * 1280 + kc * 64 + ks * 32 + kk], sel);
  } else if (i < WOS_OFF) {                 // W2 [256][256]
    int i2 = i - W2S_OFF;
    int kc = i2 / 49152, r = i2 - kc * 49152;
    int ks = r / 24576, r2 = r - ks * 24576;
    int sel = r2 / 8192, r3 = r2 & 8191;
    int j = r3 >> 5, kkpos = r3 & 31;
    int kk = ((kkpos >> 3) ^ ((j >> 1) & 3)) * 8 + (kkpos & 7);
    ws[i] = split3(W2[j * 256 + kc * 64 + ks * 32 + kk], sel);
  } else {                                  // Wo [80][256] padded to 128 rows
    int i3 = i - WOS_OFF;
    int kc = i3 / 24576, r = i3 - kc * 24576;
    int ks = r / 12288, r2 = r - ks * 12288;
    int sel = r2 / 4096, r3 = r2 & 4095;
    int j = r3 >> 5, kkpos = r3 & 31;
    int kk = ((kkpos >> 3) ^ ((j >> 1) & 3)) * 8 + (kkpos & 7);
    float w = (j < NO) ? Wo[j * 256 + kc * 64 + ks * 32 + kk] : 0.f;
    ws[i] = split3(w, sel);
  }
}

// DMA this wave's 2KB stage slice (1024 u16) into LDS: 2 instructions,
// wave-uniform LDS base + implicit lane*16.
__device__ __forceinline__ void dma2(const u16* __restrict__ src, u16* dst, int lane) {
  __builtin_amdgcn_global_load_lds((const u32*)(src + lane * 8), (u32*)dst, 16, 0, 0);
  __builtin_amdgcn_global_load_lds((const u32*)(src + 512 + lane * 8),
                                   (u32*)(dst + 512), 16, 0, 0);
}

// Barrier-free wave-private staged GEMM, register-prefetch pipelined.
// Each wave DMAs only the 32 B-rows it reads (2KB/stage) into its own
// triple-buffered LDS slice. NEW (R2): stage st+1's B-fragments are
// ds_read into registers AFTER stage st's MFMAs issue — the asm-waitcnt
// memory clobbers previously serialized (lgkm ~120cy) into every stage,
// and the compiler cannot hoist loads across them; doing it in source
// gives the reads a full stage of slack. DMA issue moved to body top
// (more vmcnt slack). Wait rule preserves R16's race fix: before
// prefetching st+1 wait VMW2 if st+2's DMA is in flight (st+1 is then
// the oldest-but-two), else VMW0 (st+1's own loads are the tail).
// Per-column accumulation order kc:(ks0:hi,mid,lo),(ks1:hi,mid,lo) —
// bit-identical to R13..R1 (only load timing changed, not values).
__device__ __forceinline__ void gemm_wp(
    const u16* lbits, int bpitch,
    const u16* __restrict__ wsbase, int nkc, int selblk,
    u16* mybuf,                     // this wave's [3][1024] u16 slices
    int wv, int lane, f32x4 acc[2][TT])
{
  const int m16 = lane & 15, q = lane >> 4;
  const int swz = (q ^ ((m16 >> 1) & 3)) * 8;
  const int lro0 = m16 * 32 + swz;           // local row m16
  const int lro1 = lro0 + 512;               // local row m16+16
  const int sh = q * 8;
  const int nst = nkc * 6;
  const u16* slice = wsbase + wv * 1024;

  dma2(slice, mybuf, lane);                  // st 0 -> buf 0
  dma2(slice + selblk, mybuf + 1024, lane);  // st 1 -> buf 1
  FENCE();
  VMW2();                                    // st0 landed (st1 still in flight)
  bf16x8 cur0 = *(const bf16x8*)(mybuf + lro0);
  bf16x8 cur1 = *(const bf16x8*)(mybuf + lro1);
  FENCE();

  int st = 0;
  for (int kcks = 0; kcks < nkc * 2; ++kcks) {
    const int kc = kcks >> 1, ks = kcks & 1;
    bf16x8 afr[TT];
    #pragma unroll
    for (int t = 0; t < TT; ++t) {
      u32 bwv = *(const u32*)(lbits + (t * RR + m16) * bpitch + kc * 4 + ks * 2);
      u32 b = (bwv >> sh) & 0xFFu;
      union { u32 u[4]; bf16x8 v; } x;
      #pragma unroll
      for (int i = 0; i < 4; ++i)
        x.u[i] = ((((b >> (2 * i)) & 3u) * 0x8001u) & 0x00010001u) * 0x3F80u;
      afr[t] = x.v;
    }
    #pragma unroll
    for (int sel = 0; sel < 3; ++sel, ++st) {
      // Issue st+2's DMA first: target buf (sel+2)%3 was prefetch-read at
      // body st-1 (lgkm-waited before st's MFMAs below) — WAR-safe.
      if (st + 2 < nst)
        dma2(slice + (st + 2) * selblk, mybuf + ((sel + 2) % 3) * 1024, lane);
      FENCE();
      #pragma unroll
      for (int t = 0; t < TT; ++t)
        acc[0][t] = __builtin_amdgcn_mfma_f32_16x16x32_bf16(afr[t], cur0, acc[0][t], 0, 0, 0);
      #pragma unroll
      for (int t = 0; t < TT; ++t)
        acc[1][t] = __builtin_amdgcn_mfma_f32_16x16x32_bf16(afr[t], cur1, acc[1][t], 0, 0, 0);
      if (st + 1 < nst) {                    // prefetch next stage's B-frags
        if (st + 2 < nst) { VMW2(); } else { VMW0(); }
        const u16* nb = mybuf + ((sel + 1) % 3) * 1024;
        cur0 = *(const bf16x8*)(nb + lro0);
        cur1 = *(const bf16x8*)(nb + lro1);
      }
      FENCE();
    }
  }
}

// LIF recurrence over t; emit spike bits via ballot. 2 col-tiles per wave.
__device__ __forceinline__ void recur_spikes2(
    f32x4 acc[2][TT], const float* __restrict__ bias,
    int lane, int wv, u16* sbits, int spitch)
{
  const int q = lane >> 4, m16 = lane & 15;
  #pragma unroll
  for (int i = 0; i < 2; ++i) {
    int ct = wv * 2 + i;
    int j = ct * 16 + m16;
    float bj = bias[j];
    #pragma unroll
    for (int rg = 0; rg < 4; ++rg) {
      float c = 0.f, v = 0.f, sprev = 0.f;
      #pragma unroll
      for (int t = 0; t < TT; ++t) {
        float u = acc[i][t][rg];
        c = __fadd_rn(__fadd_rn(__fmul_rn(c, 0.5f), u), bj);       // (c*0.5 + u) + b
        float vd = __fmul_rn(v, 0.75f);
        v = __fadd_rn((sprev > 0.5f) ? 0.f : vd, c);               // v*0.75*(1-s) + c
        bool sp = v > 0.5f;
        u64 mask = __ballot(sp);
        if (m16 == 0) {
          int row = q * 4 + rg;
          sbits[(t * RR + row) * spitch + ct] = (u16)(mask >> (q * 16));
        }
        sprev = sp ? 1.f : 0.f;
      }
    }
  }
}

__global__ __launch_bounds__(NTHR, 4) void snn_main(
    const float* __restrict__ obs, const float* __restrict__ enc_mean,
    const float* __restrict__ enc_std,
    const float* __restrict__ b1, const float* __restrict__ b2, const float* __restrict__ bo,
    const float* __restrict__ dec_w, const float* __restrict__ dec_b, const float* __restrict__ log_std,
    const u16* __restrict__ wsW, float* __restrict__ out, int Btot)
{
  __shared__ __align__(16) u16 smem[37376];          // 74,752 B -> 2 blocks/CU
  u16* bufs = smem;                                  // [8 waves][3][1024]
  u16* encb = smem + 24576;                          // [5t*16r][BP1] = 7040
  u16* s1b  = encb + 7040;                           // [5t*16r][BP2] = 1600
  u16* s2b  = s1b + 1600;                            // 1600
  float* soacc = (float*)(s2b + 1600);               // [16][80] f32 (own region)

  const int tid  = threadIdx.x;
  const int lane = tid & 63;
  const int wv   = tid >> 6;          // 0..7
  const int r0   = blockIdx.x * RR;
  u16* mybuf = bufs + wv * 3072;

  // ---------- fused population encoder: 16 rows x 1280 cols -> bit-planes ----
  // Balanced (R2): 2560 half-items of 8 exps, exactly 5 per thread (was 3
  // items/48 exps on waves 0-3, 2/32 on waves 4-7). Per-k arithmetic is
  // bit-identical to the original prep encoder; byte hi of each u16 plane
  // word holds bits 8..15 (little-endian).
  for (int h = tid; h < RR * 160; h += NTHR) {       // 2560, exactly 5 rounds
    int r = h / 160, rem = h - r * 160;
    int w = rem >> 1, hi = rem & 1;
    const float* obsrow = obs + (r0 + r) * NOBS;
    u32 bits[TT] = {0, 0, 0, 0, 0};
    #pragma unroll
    for (int e = 0; e < 8; ++e) {
      int k = w * 16 + hi * 8 + e;
      int f = k / 10;
      float x  = obsrow[f];
      float m  = enc_mean[k];
      float sd = enc_std[k];
      float d  = __fsub_rn(x, m);
      float arg = __fdiv_rn(__fmul_rn(-0.5f, __fmul_rn(d, d)), __fmul_rn(sd, sd));
      float a = exp_cr(arg);
      float v = 0.f;
      #pragma unroll
      for (int t = 0; t < TT; ++t) {
        v = __fadd_rn(v, a);
        if (v > 0.999f) { bits[t] |= (1u << e); v = __fsub_rn(v, 0.999f); }
      }
    }
    u8* eb = (u8*)encb;
    #pragma unroll
    for (int t = 0; t < TT; ++t)
      eb[((t * RR + r) * BP1 + w) * 2 + hi] = (u8)bits[t];
  }
  __syncthreads();

  f32x4 acc[2][TT];
  const f32x4 zero4 = {0.f, 0.f, 0.f, 0.f};
#define ZERO_ACC() { _Pragma("unroll") for (int i = 0; i < 2; ++i) \
                     _Pragma("unroll") for (int t = 0; t < TT; ++t) acc[i][t] = zero4; }

  // ---------- layer 1: [80 x 1280] @ [1280 x 256] (3-way split fused) ----------
  ZERO_ACC();
  gemm_wp(encb, BP1, wsW, 20, 8192, mybuf, wv, lane, acc);
  recur_spikes2(acc, b1, lane, wv, s1b, BP2);
  __syncthreads();

  // ---------- layer 2: [80 x 256] @ [256 x 256] ----------
  ZERO_ACC();
  gemm_wp(s1b, BP2, wsW + W2S_OFF, 4, 8192, mybuf, wv, lane, acc);
  recur_spikes2(acc, b2, lane, wv, s2b, BP2);
  __syncthreads();

  // ---------- layer 3: [80 x 256] @ [256 x 80(pad96 of 128)] — waves 0..2 ----------
  if (wv < 3) {
    ZERO_ACC();
    gemm_wp(s2b, BP2, wsW + WOS_OFF, 4, 4096, mybuf, wv, lane, acc);
    const int q = lane >> 4, m16 = lane & 15;
    #pragma unroll
    for (int i = 0; i < 2; ++i) {
      int j = (wv * 2 + i) * 16 + m16;
      bool valid = j < NO;
      float bj = valid ? bo[j] : 0.f;
      #pragma unroll
      for (int rg = 0; rg < 4; ++rg) {
        float c = 0.f, v = 0.f, sprev = 0.f;
        int cnt = 0;
        #pragma unroll
        for (int t = 0; t < TT; ++t) {
          float u = acc[i][t][rg];
          c = __fadd_rn(__fadd_rn(__fmul_rn(c, 0.5f), u), bj);
          float vd = __fmul_rn(v, 0.75f);
          v = __fadd_rn((sprev > 0.5f) ? 0.f : vd, c);
          bool sp = v > 0.5f;
          cnt += sp ? 1 : 0;
          sprev = sp ? 1.f : 0.f;
        }
        if (valid) soacc[(q * 4 + rg) * NO + j] = __fdiv_rn((float)cnt, 5.0f);
      }
    }
  }
  __syncthreads();

  // ---------- decoder: grouped dot + ELU ----------
  if (tid < RR * 8) {
    int r = tid >> 3, a = tid & 7;
    float s = 0.f;
    const float* so = soacc + r * NO + a * 10;
    #pragma unroll
    for (int p = 0; p < 10; ++p)
      s = __fadd_rn(s, __fmul_rn(so[p], dec_w[a * 10 + p]));
    s = __fadd_rn(s, dec_b[a]);
    float mu = (s > 0.f) ? s : expm1f(s);
    out[(r0 + r) * 8 + a] = mu;
  }
  if (blockIdx.x == 0 && tid < 8) {
    out[Btot * 8 + tid] = expf(log_std[tid]);
  }
}

extern "C" void kernel_launch(void* const* d_in, const int* in_sizes, int n_in,
                              void* d_out, int out_size, void* d_ws, size_t ws_size,
                              hipStream_t stream) {
  const float* obs      = (const float*)d_in[0];
  const float* enc_mean = (const float*)d_in[1];
  const float* enc_std  = (const float*)d_in[2];
  const float* W1       = (const float*)d_in[3];
  const float* b1       = (const float*)d_in[4];
  const float* W2       = (const float*)d_in[5];
  const float* b2       = (const float*)d_in[6];
  const float* Wo       = (const float*)d_in[7];
  const float* bo       = (const float*)d_in[8];
  const float* dec_w    = (const float*)d_in[9];
  const float* dec_b    = (const float*)d_in[10];
  const float* log_std  = (const float*)d_in[11];
  u16*   ws  = (u16*)d_ws;
  float* out = (float*)d_out;
  int B = in_sizes[0] / NOBS;   // 8192

  hipLaunchKernelGGL(prep_w, dim3(PREP_BLOCKS), dim3(256), 0, stream,
                     W1, W2, Wo, ws);
  hipLaunchKernelGGL(snn_main, dim3(B / RR), dim3(NTHR), 0, stream,
                     obs, enc_mean, enc_std, b1, b2, bo, dec_w, dec_b, log_std,
                     ws, out, B);
}